// Round 5
// baseline (232.581 us; speedup 1.0000x reference)
//
#include <hip/hip_runtime.h>
#include <hip/hip_bf16.h>

typedef __bf16 bf16;
typedef __bf16 bf16x8 __attribute__((ext_vector_type(8)));
typedef float f32x4 __attribute__((ext_vector_type(4)));

#define MFMA16(a, b, c) __builtin_amdgcn_mfma_f32_16x16x32_bf16((a), (b), (c), 0, 0, 0)

// Problem: B=2, L=4096, D=1024, H=8, Hd=128, CHUNK=64, NCHUNK=64
// gamma_h = 1 - 2^(-5-h).  Inputs fp32, OUTPUT fp32.

// async 16B global->LDS (gfx950). LDS dest is wave-uniform base + lane*16.
__device__ __forceinline__ void g2l16(const bf16* g, bf16* l) {
  __builtin_amdgcn_global_load_lds(
      (const __attribute__((address_space(1))) void*)g,
      (__attribute__((address_space(3))) void*)l, 16, 0, 0);
}

// ---------------------------------------------------------------------------
// prep: z<4 -> transpose+cvt weight z (Wt[z][n][k]=bf16(W[k][n]));
//       z==4 -> bulk fp32->bf16 convert of X (grid-stride).
// ---------------------------------------------------------------------------
__global__ __launch_bounds__(256) void prep(
    const float* __restrict__ X, const float* __restrict__ Wq,
    const float* __restrict__ Wk, const float* __restrict__ Wv,
    const float* __restrict__ Wo, bf16* __restrict__ Wt,
    bf16* __restrict__ Xb) {
  const int tid = threadIdx.x;
  if (blockIdx.z == 4) {
#pragma unroll
    for (int it = 0; it < 16; ++it) {
      const size_t i = (((size_t)blockIdx.x * 16 + it) * 256 + tid) * 8;
      float4 a = *(const float4*)&X[i];
      float4 b = *(const float4*)&X[i + 4];
      union { bf16 h[8]; uint4 u; } p;
      p.h[0] = (bf16)a.x; p.h[1] = (bf16)a.y; p.h[2] = (bf16)a.z; p.h[3] = (bf16)a.w;
      p.h[4] = (bf16)b.x; p.h[5] = (bf16)b.y; p.h[6] = (bf16)b.z; p.h[7] = (bf16)b.w;
      *(uint4*)&Xb[i] = p.u;
    }
    return;
  }
  __shared__ bf16 t[64 * 72];
  const float* src = (blockIdx.z == 0) ? Wq : (blockIdx.z == 1) ? Wk
                     : (blockIdx.z == 2) ? Wv : Wo;
  bf16* dst = Wt + (size_t)blockIdx.z * 1024 * 1024;
  const int k0 = (blockIdx.x >> 4) * 64, n0 = (blockIdx.x & 15) * 64;
#pragma unroll
  for (int s = 0; s < 4; ++s) {
    int u = tid + s * 256;          // 0..1023
    int r = u >> 4, c4 = (u & 15) * 4;
    float4 f = *(const float4*)&src[(size_t)(k0 + r) * 1024 + n0 + c4];
    t[r * 72 + c4 + 0] = (bf16)f.x;
    t[r * 72 + c4 + 1] = (bf16)f.y;
    t[r * 72 + c4 + 2] = (bf16)f.z;
    t[r * 72 + c4 + 3] = (bf16)f.w;
  }
  __syncthreads();
#pragma unroll
  for (int s = 0; s < 2; ++s) {
    int u = tid + s * 256;
    int r = u >> 3, cc = u & 7;     // output row n0+r, k-chunk cc
    union { bf16 h[8]; uint4 u4; } pk;
#pragma unroll
    for (int j = 0; j < 8; ++j) pk.h[j] = t[(cc * 8 + j) * 72 + r];
    *(uint4*)&dst[(size_t)(n0 + r) * 1024 + k0 + cc * 8] = pk.u4;
  }
}

// ---------------------------------------------------------------------------
// GEMM: C = alpha * (A @ Bt^T).  128x128 tile, BK=64, global_load_lds(16B)
// staging with XOR swizzle (verified 0 bank conflicts, r4).
// MODE==1 (QKV): z=0 -> qb (alpha); z=1 -> kb normal AND kTb transposed;
//   z=2 -> vTb transposed only.  Transposed layout per (bh,chunk) g:
//   Tp[g*8192 + d*64 + c] = val[seq=c][feat=d]  (c within chunk, d within head).
// MODE==0: plain store to C (fp32 d_out).
// ---------------------------------------------------------------------------
template <typename TC, int MODE>
__global__ __launch_bounds__(256) void gemm_lds(
    const bf16* __restrict__ A, const bf16* __restrict__ Bt,
    TC* __restrict__ C, bf16* __restrict__ kTb, bf16* __restrict__ vTb,
    float alpha) {
  __shared__ bf16 lA[128 * 64];
  __shared__ bf16 lB[128 * 64];
  const int m0 = blockIdx.x * 128, n0 = blockIdx.y * 128;
  if (MODE) {
    Bt += (size_t)blockIdx.z * 1024 * 1024;
    if (blockIdx.z != 0) alpha = 1.0f;
  }
  const int tid = threadIdx.x;
  const int w = tid >> 6, lane = tid & 63, lr = lane & 15, quad = lane >> 4;
  const int wm = w >> 1, wn = w & 1;

  const int srow = w * 32 + (lane >> 3);
  const int clog = (lane & 7) ^ ((lane >> 3) & 7);
  const bf16* gA = A + (size_t)(m0 + srow) * 1024 + clog * 8;
  const bf16* gB = Bt + (size_t)(n0 + srow) * 1024 + clog * 8;

  f32x4 acc[4][4] = {};

  for (int it = 0; it < 16; ++it) {
    const int k0 = it * 64;
#pragma unroll
    for (int is = 0; is < 4; ++is) {
      g2l16(gA + (size_t)is * 8 * 1024 + k0, &lA[(w * 32 + is * 8) * 64]);
      g2l16(gB + (size_t)is * 8 * 1024 + k0, &lB[(w * 32 + is * 8) * 64]);
    }
    __syncthreads();
#pragma unroll
    for (int kk = 0; kk < 2; ++kk) {
      bf16x8 af[4], bfv[4];
#pragma unroll
      for (int i = 0; i < 4; ++i) {
        const int m = wm * 64 + i * 16 + lr;
        af[i] = *(bf16x8*)&lA[m * 64 + (((kk * 4 + quad) ^ (lr & 7)) * 8)];
      }
#pragma unroll
      for (int j = 0; j < 4; ++j) {
        const int n = wn * 64 + j * 16 + lr;
        bfv[j] = *(bf16x8*)&lB[n * 64 + (((kk * 4 + quad) ^ (lr & 7)) * 8)];
      }
#pragma unroll
      for (int i = 0; i < 4; ++i)
#pragma unroll
        for (int j = 0; j < 4; ++j)
          acc[i][j] = MFMA16(af[i], bfv[j], acc[i][j]);
    }
    __syncthreads();
  }
  // Epilogue: D layout col=lane&15, row=quad*4+r
#pragma unroll
  for (int i = 0; i < 4; ++i) {
#pragma unroll
    for (int j = 0; j < 4; ++j) {
      const int row = m0 + wm * 64 + i * 16 + quad * 4;
      const int col = n0 + wn * 64 + j * 16 + lr;
      if (MODE == 0 || blockIdx.z < 2) {
        TC* Cz = C + (MODE ? (size_t)blockIdx.z * 8192 * 1024 : 0);
#pragma unroll
        for (int r = 0; r < 4; ++r)
          Cz[(size_t)(row + r) * 1024 + col] = (TC)(acc[i][j][r] * alpha);
      }
      if (MODE == 1 && blockIdx.z >= 1) {
        bf16* Tp = (blockIdx.z == 1) ? kTb : vTb;
        const int b = row >> 12, pos = row & 4095;
        const int n = pos >> 6, c0 = pos & 63;       // c0 multiple of 4
        const int h = col >> 7, d = col & 127;
        union { bf16 h4[4]; uint2 u2; } pk;
#pragma unroll
        for (int r = 0; r < 4; ++r) pk.h4[r] = (bf16)acc[i][j][r];
        *(uint2*)&Tp[((size_t)((b * 8 + h) * 64 + n)) * 8192 + d * 64 + c0] = pk.u2;
      }
    }
  }
}

// ---------------------------------------------------------------------------
// Phase A: T^T[dv][dk] = sum_c k[c][dk]*g^(63-c)*v[c][dv], from kT/vT layouts.
// Straight vector staging + XOR swizzle (no LDS transpose, no conflicts).
// ---------------------------------------------------------------------------
__global__ __launch_bounds__(256) void chunk_kv(
    const bf16* __restrict__ kT, const bf16* __restrict__ vT,
    bf16* __restrict__ Tb) {
  __shared__ bf16 lK[128 * 64];  // [dk][c-chunk swizzled], decay folded
  __shared__ bf16 lV[128 * 64];  // [dv][c-chunk swizzled]
  const int g = blockIdx.x;
  const int h = (g >> 6) & 7;
  const float lg = log2f(1.0f - exp2f(-5.0f - (float)h));
  const float ginv = exp2f(-lg);
  const int tid = threadIdx.x;
  const bf16* ks = kT + (size_t)g * 8192;
  const bf16* vs = vT + (size_t)g * 8192;
#pragma unroll
  for (int s = 0; s < 4; ++s) {
    int u = tid + s * 256;
    int d = u >> 3, c0 = (u & 7) * 8;
    int pc = ((u & 7) ^ (d & 7)) * 8;
    *(uint4*)&lV[d * 64 + pc] = *(const uint4*)&vs[d * 64 + c0];
    union { uint4 u4; bf16 h8[8]; } kv;
    kv.u4 = *(const uint4*)&ks[d * 64 + c0];
    float e = exp2f((float)(63 - c0) * lg);
    union { bf16 h8[8]; uint4 u4; } o;
#pragma unroll
    for (int jj = 0; jj < 8; ++jj) {
      o.h8[jj] = (bf16)((float)kv.h8[jj] * e);
      e *= ginv;
    }
    *(uint4*)&lK[d * 64 + pc] = o.u4;
  }
  __syncthreads();
  const int w = tid >> 6, lane = tid & 63, lr = lane & 15, quad = lane >> 4;
  const int wm = w >> 1, wn = w & 1;
  f32x4 acc[4][4] = {};
#pragma unroll
  for (int kk = 0; kk < 2; ++kk) {
    const int pc = ((kk * 4 + quad) ^ (lr & 7)) * 8;
    bf16x8 af[4], bv[4];
#pragma unroll
    for (int i = 0; i < 4; ++i)
      af[i] = *(bf16x8*)&lK[(wm * 64 + i * 16 + lr) * 64 + pc];
#pragma unroll
    for (int j = 0; j < 4; ++j)
      bv[j] = *(bf16x8*)&lV[(wn * 64 + j * 16 + lr) * 64 + pc];
#pragma unroll
    for (int i = 0; i < 4; ++i)
#pragma unroll
      for (int j = 0; j < 4; ++j)
        acc[i][j] = MFMA16(af[i], bv[j], acc[i][j]);
  }
  bf16* tchunk = Tb + (size_t)g * 16384;
#pragma unroll
  for (int i = 0; i < 4; ++i) {
#pragma unroll
    for (int j = 0; j < 4; ++j) {
      const int dk = wm * 64 + i * 16 + quad * 4;
      const int dv = wn * 64 + j * 16 + lr;
      union { bf16 h4[4]; uint2 u2; } pk;
#pragma unroll
      for (int r = 0; r < 4; ++r) pk.h4[r] = (bf16)acc[i][j][r];
      *(uint2*)&tchunk[(size_t)dv * 128 + dk] = pk.u2;  // T^T[dv][dk]
    }
  }
}

// ---------------------------------------------------------------------------
// Phase B: exclusive prefix scan over chunks, 4 elems (uint2) per thread.
// grid = 256 (16 per bh), fp32 accumulators, unroll-8 for load ILP.
// ---------------------------------------------------------------------------
__global__ __launch_bounds__(256) void scan_state(bf16* __restrict__ Tb) {
  const int blk = blockIdx.x;
  const int bh = blk >> 4, h = bh & 7;
  const float gs = exp2f(64.0f * log2f(1.0f - exp2f(-5.0f - (float)h)));
  const size_t base =
      (size_t)bh * 1048576 + (size_t)(blk & 15) * 1024 + threadIdx.x * 4;
  float S0 = 0.0f, S1 = 0.0f, S2 = 0.0f, S3 = 0.0f;
#pragma unroll 8
  for (int n = 0; n < 64; ++n) {
    const size_t a = base + (size_t)n * 16384;
    union { uint2 u; bf16 h4[4]; } t, o;
    t.u = *(const uint2*)&Tb[a];
    o.h4[0] = (bf16)S0; o.h4[1] = (bf16)S1;
    o.h4[2] = (bf16)S2; o.h4[3] = (bf16)S3;
    *(uint2*)&Tb[a] = o.u;
    S0 = gs * S0 + (float)t.h4[0];
    S1 = gs * S1 + (float)t.h4[1];
    S2 = gs * S2 + (float)t.h4[2];
    S3 = gs * S3 + (float)t.h4[3];
  }
}

// ---------------------------------------------------------------------------
// Phase C: P = (q@k^T)*D; o = P@v + gamma^(i+1) * (q @ S_prev).
// k B-frags direct from global; v from vT (swizzled, no transpose);
// inter-decay applied on the accumulator (row-wise scale).
// ---------------------------------------------------------------------------
__global__ __launch_bounds__(256) void chunk_out(
    const bf16* __restrict__ qb, const bf16* __restrict__ kb,
    const bf16* __restrict__ vT, const bf16* __restrict__ Sp,
    bf16* __restrict__ ob) {
  __shared__ bf16 lQ[64 * 136];   // [c][dk]
  __shared__ bf16 lVt[128 * 64];  // [dv][c swizzled]
  __shared__ bf16 lP[64 * 72];    // [ci][cj]
  const int g = blockIdx.x;
  const int bh = g >> 6, n = g & 63, b = bh >> 3, h = bh & 7;
  const float lg = log2f(1.0f - exp2f(-5.0f - (float)h));
  const float gam = exp2f(lg);
  const int tid = threadIdx.x;
  const size_t rowbase = (size_t)(b * 4096 + n * 64) * 1024 + h * 128;
  const bf16* qc = qb + rowbase;
  const bf16* kc = kb + rowbase;
  const bf16* vs = vT + (size_t)g * 8192;
#pragma unroll
  for (int s = 0; s < 4; ++s) {
    int u = tid + s * 256;
    int c = u >> 4, d0 = (u & 15) * 8;
    *(uint4*)&lQ[c * 136 + d0] = *(const uint4*)&qc[(size_t)c * 1024 + d0];
    int d = u >> 3, cc = (u & 7) * 8;
    int pc = ((u & 7) ^ (d & 7)) * 8;
    *(uint4*)&lVt[d * 64 + pc] = *(const uint4*)&vs[d * 64 + cc];
  }
  __syncthreads();
  const int w = tid >> 6, lane = tid & 63, lr = lane & 15, quad = lane >> 4;

  // --- Step 1: P = q @ k^T (k B-frags straight from global) ---
  f32x4 p[4] = {};
#pragma unroll
  for (int kk = 0; kk < 4; ++kk) {
    bf16x8 bfrag =
        *(const bf16x8*)&kc[(size_t)(w * 16 + lr) * 1024 + kk * 32 + quad * 8];
#pragma unroll
    for (int i = 0; i < 4; ++i) {
      bf16x8 afrag = *(bf16x8*)&lQ[(i * 16 + lr) * 136 + kk * 32 + quad * 8];
      p[i] = MFMA16(afrag, bfrag, p[i]);
    }
  }
#pragma unroll
  for (int i = 0; i < 4; ++i) {
#pragma unroll
    for (int r = 0; r < 4; ++r) {
      const int row = i * 16 + quad * 4 + r;
      const int col = w * 16 + lr;
      const int diff = row - col;
      const float val = (diff >= 0) ? p[i][r] * exp2f((float)diff * lg) : 0.0f;
      lP[row * 72 + col] = (bf16)val;
    }
  }
  __syncthreads();

  // --- Step 2 (intra) + Step 3 (inter, raw q@S) ---
  f32x4 oac[4][2] = {}, oin[4][2] = {};
#pragma unroll
  for (int j = 0; j < 2; ++j) {
#pragma unroll
    for (int kk = 0; kk < 2; ++kk) {
      const int m = w * 32 + j * 16 + lr;
      bf16x8 bfrag = *(bf16x8*)&lVt[m * 64 + (((kk * 4 + quad) ^ (m & 7)) * 8)];
#pragma unroll
      for (int i = 0; i < 4; ++i) {
        bf16x8 afrag = *(bf16x8*)&lP[(i * 16 + lr) * 72 + kk * 32 + quad * 8];
        oac[i][j] = MFMA16(afrag, bfrag, oac[i][j]);
      }
    }
  }
  const bf16* sp = Sp + (size_t)g * 16384;
#pragma unroll
  for (int kk = 0; kk < 4; ++kk) {
    bf16x8 af[4];
#pragma unroll
    for (int i = 0; i < 4; ++i)
      af[i] = *(bf16x8*)&lQ[(i * 16 + lr) * 136 + kk * 32 + quad * 8];
#pragma unroll
    for (int j = 0; j < 2; ++j) {
      bf16x8 bfrag =
          *(const bf16x8*)&sp[(size_t)(w * 32 + j * 16 + lr) * 128 + kk * 32 + quad * 8];
#pragma unroll
      for (int i = 0; i < 4; ++i) oin[i][j] = MFMA16(af[i], bfrag, oin[i][j]);
    }
  }

  // --- combine: o = oac + gamma^(row+1) * oin ---
  bf16* oc = ob + rowbase;
#pragma unroll
  for (int i = 0; i < 4; ++i) {
    const float d0 = exp2f((float)(i * 16 + quad * 4 + 1) * lg);
#pragma unroll
    for (int j = 0; j < 2; ++j) {
      float d = d0;
#pragma unroll
      for (int r = 0; r < 4; ++r) {
        const int row = i * 16 + quad * 4 + r;
        const int col = w * 32 + j * 16 + lr;
        oc[(size_t)row * 1024 + col] = (bf16)(oac[i][j][r] + d * oin[i][j][r]);
        d *= gam;
      }
    }
  }
}

// ---------------------------------------------------------------------------
extern "C" void kernel_launch(void* const* d_in, const int* in_sizes, int n_in,
                              void* d_out, int out_size, void* d_ws,
                              size_t ws_size, hipStream_t stream) {
  const float* X  = (const float*)d_in[0];
  const float* Wq = (const float*)d_in[2];
  const float* Wk = (const float*)d_in[3];
  const float* Wv = (const float*)d_in[4];
  const float* Wo = (const float*)d_in[5];

  char* ws = (char*)d_ws;
  const size_t MB = 1024 * 1024;
  bf16* qb  = (bf16*)(ws);              // 16 MiB
  bf16* kb  = (bf16*)(ws + 16 * MB);    // 16 MiB (normal layout)
  bf16* kTb = (bf16*)(ws + 32 * MB);    // 16 MiB (transposed per-chunk)
  bf16* vTb = (bf16*)(ws + 48 * MB);    // 16 MiB (transposed per-chunk)
  bf16* Tb  = (bf16*)(ws + 64 * MB);    // 32 MiB
  bf16* Wt  = (bf16*)(ws + 96 * MB);    // 8 MiB
  bf16* Xb  = (bf16*)(ws + 104 * MB);   // 16 MiB; dead after QKV gemm
  bf16* ob  = Xb;                       // alias: ob written after Xb's last use

  prep<<<dim3(256, 1, 5), 256, 0, stream>>>(X, Wq, Wk, Wv, Wo, Wt, Xb);

  const float qscale = 0.08838834764831845f;  // 128^-0.5
  gemm_lds<bf16, 1><<<dim3(64, 8, 3), 256, 0, stream>>>(Xb, Wt, qb, kTb, vTb,
                                                        qscale);

  chunk_kv<<<1024, 256, 0, stream>>>(kTb, vTb, Tb);
  scan_state<<<256, 256, 0, stream>>>(Tb);
  chunk_out<<<1024, 256, 0, stream>>>(qb, kb, vTb, Tb, ob);

  gemm_lds<float, 0><<<dim3(64, 8), 256, 0, stream>>>(
      ob, Wt + (size_t)3 * 1024 * 1024, (float*)d_out, nullptr, nullptr, 1.0f);
}